// Round 3
// baseline (494.824 us; speedup 1.0000x reference)
//
#include <hip/hip_runtime.h>
#include <math.h>

#define B_    2
#define S_    2048
#define E_    2048
#define H_    32
#define HKV_  8
#define D_    64

typedef __bf16 bf16x8 __attribute__((ext_vector_type(8)));
typedef float  f32x4  __attribute__((ext_vector_type(4)));
typedef float  f32x16 __attribute__((ext_vector_type(16)));
typedef unsigned int u32x2 __attribute__((ext_vector_type(2)));
typedef unsigned int u32x4 __attribute__((ext_vector_type(4)));

#define GPTR(x) ((const __attribute__((address_space(1))) void*)(x))
#define LPTR(x) ((__attribute__((address_space(3))) void*)(x))

// 0.125 * log2(e): folded into Q so attention softmax is exp2-direct.
#define QK_SCALE_LOG2E 0.18033688011112042f

// ---------------------------------------------------------------------------
// fp32 -> bf16 flat convert (x)
// ---------------------------------------------------------------------------
__global__ __launch_bounds__(256) void convert_kernel(
    const float* __restrict__ in, __bf16* __restrict__ out, int n8)
{
    const int i = blockIdx.x * 256 + threadIdx.x;
    if (i >= n8) return;
    const float4 a = ((const float4*)in)[i * 2];
    const float4 b = ((const float4*)in)[i * 2 + 1];
    bf16x8 o;
    o[0] = (__bf16)a.x; o[1] = (__bf16)a.y; o[2] = (__bf16)a.z; o[3] = (__bf16)a.w;
    o[4] = (__bf16)b.x; o[5] = (__bf16)b.y; o[6] = (__bf16)b.z; o[7] = (__bf16)b.w;
    ((bf16x8*)out)[i] = o;
}

// ---------------------------------------------------------------------------
// All 4 weight transposes (fp32 (K,N) -> bf16 (N,K)) in ONE dispatch.
// K = 2048 for every weight. x-block range selects the source matrix.
// ---------------------------------------------------------------------------
__global__ __launch_bounds__(256) void transpose_convert_all_kernel(
    const float* __restrict__ wq, const float* __restrict__ wk,
    const float* __restrict__ wv, const float* __restrict__ wo,
    __bf16* __restrict__ wT, __bf16* __restrict__ woT)
{
    const float* in; __bf16* out; int N, xb;
    const int x = blockIdx.x;
    if (x < 64)      { in = wq; out = wT;                        N = 2048; xb = x; }
    else if (x < 80) { in = wk; out = wT + (size_t)2048 * 2048;  N = 512;  xb = x - 64; }
    else if (x < 96) { in = wv; out = wT + (size_t)2560 * 2048;  N = 512;  xb = x - 80; }
    else             { in = wo; out = woT;                       N = 2048; xb = x - 96; }
    const int K = 2048;

    __shared__ float tile[32][33];
    const int k0 = blockIdx.y * 32, n0 = xb * 32;
    const int r  = threadIdx.x >> 3;
    const int c4 = (threadIdx.x & 7) * 4;
    const float4 v = *(const float4*)&in[(size_t)(k0 + r) * N + n0 + c4];
    tile[r][c4 + 0] = v.x; tile[r][c4 + 1] = v.y;
    tile[r][c4 + 2] = v.z; tile[r][c4 + 3] = v.w;
    __syncthreads();
    ushort4 o;
    __bf16 h0 = (__bf16)tile[c4 + 0][r]; o.x = __builtin_bit_cast(unsigned short, h0);
    __bf16 h1 = (__bf16)tile[c4 + 1][r]; o.y = __builtin_bit_cast(unsigned short, h1);
    __bf16 h2 = (__bf16)tile[c4 + 2][r]; o.z = __builtin_bit_cast(unsigned short, h2);
    __bf16 h3 = (__bf16)tile[c4 + 3][r]; o.w = __builtin_bit_cast(unsigned short, h3);
    *(ushort4*)&out[(size_t)(n0 + r) * K + k0 + c4] = o;
}

// ---------------------------------------------------------------------------
// bf16 MFMA GEMM body (m97 structure) — unchanged
// ---------------------------------------------------------------------------
__device__ __forceinline__ void gemm_mfma_body(
    const __bf16* __restrict__ A, const __bf16* __restrict__ Bt,
    int m0, int n0, int K, __bf16* sA, __bf16* sB, f32x4 acc[4][4])
{
    const int t    = threadIdx.x;
    const int w    = t >> 6;
    const int lane = t & 63;
    const int col  = lane & 15;
    const int quad = lane >> 4;
    const int wrow = (w >> 1) * 64;
    const int wcol = (w & 1) * 64;

    const int row0 = t >> 3;
    const int c0   = t & 7;

    for (int k0 = 0; k0 < K; k0 += 64) {
#pragma unroll
        for (int it = 0; it < 4; ++it) {
            const int row  = it * 32 + row0;
            const int csrc = c0 ^ (row & 7);
            __builtin_amdgcn_global_load_lds(
                GPTR(A + (size_t)(m0 + row) * K + k0 + csrc * 8),
                LPTR(sA + (it * 256 + t) * 8), 16, 0, 0);
        }
#pragma unroll
        for (int it = 0; it < 4; ++it) {
            const int row  = it * 32 + row0;
            const int csrc = c0 ^ (row & 7);
            __builtin_amdgcn_global_load_lds(
                GPTR(Bt + (size_t)(n0 + row) * K + k0 + csrc * 8),
                LPTR(sB + (it * 256 + t) * 8), 16, 0, 0);
        }
        __syncthreads();

#pragma unroll
        for (int kk = 0; kk < 2; ++kk) {
            bf16x8 af[4], bfr[4];
#pragma unroll
            for (int i = 0; i < 4; ++i) {
                const int m = wrow + i * 16 + col;
                af[i] = *(const bf16x8*)&sA[m * 64 + (((kk * 4 + quad) ^ (m & 7)) * 8)];
            }
#pragma unroll
            for (int j = 0; j < 4; ++j) {
                const int n = wcol + j * 16 + col;
                bfr[j] = *(const bf16x8*)&sB[n * 64 + (((kk * 4 + quad) ^ (n & 7)) * 8)];
            }
#pragma unroll
            for (int i = 0; i < 4; ++i)
#pragma unroll
                for (int j = 0; j < 4; ++j)
                    acc[i][j] = __builtin_amdgcn_mfma_f32_16x16x32_bf16(
                        af[i], bfr[j], acc[i][j], 0, 0, 0);
        }
        __syncthreads();
    }
}

// ---------------------------------------------------------------------------
// QKV GEMM with FUSED RoPE in the epilogue.
// RoPE pairs (n even, n odd) live in adjacent lanes (n parity == lane parity
// in the C-write map) -> one __shfl_xor(val,1) gives the partner value.
// Q additionally carries 0.125*log2e (commutes with the rotation).
// ---------------------------------------------------------------------------
__global__ __launch_bounds__(256) void gemm_qkv_kernel(
    const __bf16* __restrict__ xb, const __bf16* __restrict__ wT,
    const float* __restrict__ fc, const float* __restrict__ fs,
    __bf16* __restrict__ qb, __bf16* __restrict__ kb, __bf16* __restrict__ vb)
{
    __shared__ __bf16 sA[128 * 64];
    __shared__ __bf16 sB[128 * 64];
    f32x4 acc[4][4];
#pragma unroll
    for (int i = 0; i < 4; ++i)
#pragma unroll
        for (int j = 0; j < 4; ++j) acc[i][j] = (f32x4){0.f, 0.f, 0.f, 0.f};

    const int bx = blockIdx.x;
    const int m0 = blockIdx.y * 128;
    gemm_mfma_body(xb, wT, m0, bx * 128, E_, sA, sB, acc);

    __bf16* Cp; int ldc, nb;
    if (bx < 16)      { Cp = qb; ldc = H_ * D_;   nb = bx * 128; }
    else if (bx < 20) { Cp = kb; ldc = HKV_ * D_; nb = (bx - 16) * 128; }
    else              { Cp = vb; ldc = HKV_ * D_; nb = (bx - 20) * 128; }

    const bool  doRope = (bx < 20);
    const float qsc    = (bx < 16) ? QK_SCALE_LOG2E : 1.0f;

    const int lane = threadIdx.x & 63;
    const int col  = lane & 15;
    const int quad = lane >> 4;
    const int wrow = ((threadIdx.x >> 6) >> 1) * 64;
    const int wcol = ((threadIdx.x >> 6) & 1) * 64;
#pragma unroll
    for (int i = 0; i < 4; ++i)
#pragma unroll
        for (int j = 0; j < 4; ++j)
#pragma unroll
            for (int r = 0; r < 4; ++r) {
                const int m = m0 + wrow + i * 16 + quad * 4 + r;
                const int n = nb + wcol + j * 16 + col;
                float val = acc[i][j][r] * qsc;
                if (doRope) {
                    const int   s    = m & (S_ - 1);
                    const int   pair = (n & 63) >> 1;
                    const float c    = fc[s * 32 + pair];
                    const float sn   = fs[s * 32 + pair];
                    const float oth  = __shfl_xor(val, 1);
                    // even lane: val=x0, oth=x1 -> x0*c - x1*sn
                    // odd lane:  val=x1, oth=x0 -> x0*sn + x1*c
                    val = (lane & 1) ? (oth * sn + val * c)
                                     : (val * c - oth * sn);
                }
                Cp[(size_t)m * ldc + n] = (__bf16)val;
            }
}

__global__ __launch_bounds__(256) void gemm_out_kernel(
    const __bf16* __restrict__ ob, const __bf16* __restrict__ woT,
    const float* __restrict__ bias, float* __restrict__ out)
{
    __shared__ __bf16 sA[128 * 64];
    __shared__ __bf16 sB[128 * 64];
    f32x4 acc[4][4];
#pragma unroll
    for (int i = 0; i < 4; ++i)
#pragma unroll
        for (int j = 0; j < 4; ++j) acc[i][j] = (f32x4){0.f, 0.f, 0.f, 0.f};

    const int m0 = blockIdx.y * 128;
    const int n0 = blockIdx.x * 128;
    gemm_mfma_body(ob, woT, m0, n0, H_ * D_, sA, sB, acc);

    const int lane = threadIdx.x & 63;
    const int col  = lane & 15;
    const int quad = lane >> 4;
    const int wrow = ((threadIdx.x >> 6) >> 1) * 64;
    const int wcol = ((threadIdx.x >> 6) & 1) * 64;
#pragma unroll
    for (int i = 0; i < 4; ++i)
#pragma unroll
        for (int j = 0; j < 4; ++j)
#pragma unroll
            for (int r = 0; r < 4; ++r) {
                const int m = m0 + wrow + i * 16 + quad * 4 + r;
                const int n = n0 + wcol + j * 16 + col;
                out[(size_t)m * E_ + n] = acc[i][j][r] + bias[n];
            }
}

// ---------------------------------------------------------------------------
// MFMA flash attention v3 (m214-style): swapped QK^T on 32x32x16 MFMA.
// Per block: 4 waves x 32 q-rows = 128 q. A=K, B=Q -> lane holds P[q][16 keys]
// in registers; exp2-direct (scale folded into Q); in-register P->bf16 via
// v_cvt_pk_bf16_f32 + __builtin_amdgcn_permlane32_swap; PV from PA regs.
// K/V^T double-buffered in LDS, reg-staged async, ONE barrier per 64-key tile.
// launch_bounds(256,4): exactly 4 blocks/CU (LDS 4x36.9KB=147KB, VGPR<=128).
// ---------------------------------------------------------------------------
struct StageRegs {
    bf16x8  k0, k1;
    ushort4 va0, vc0, va1, vc1;
};

__device__ __forceinline__ void stage_load(
    StageRegs& r, const __bf16* kbase, const __bf16* vbase, int j0,
    int kkey, int kd, int vkp, int vdg)
{
    const int KSTR = HKV_ * D_;   // 512
    const __bf16* kr = kbase + (size_t)(j0 + kkey) * KSTR + kd;
    r.k0 = ((const bf16x8*)kr)[0];
    r.k1 = ((const bf16x8*)kr)[1];
    const __bf16* v0 = vbase + (size_t)(j0 + vkp) * KSTR + vdg;
    r.va0 = *(const ushort4*)(v0);
    r.vc0 = *(const ushort4*)(v0 + KSTR);
    r.va1 = *(const ushort4*)(v0 + 32);
    r.vc1 = *(const ushort4*)(v0 + KSTR + 32);
}

__device__ __forceinline__ void stage_write(
    const StageRegs& r, __bf16 (*sK)[72], __bf16 (*sVT)[72],
    int kkey, int kd, int vkp, int vdg)
{
    *(bf16x8*)&sK[kkey][kd]     = r.k0;
    *(bf16x8*)&sK[kkey][kd + 8] = r.k1;
    *(unsigned int*)&sVT[vdg + 0][vkp]      = ((unsigned)r.vc0.x << 16) | r.va0.x;
    *(unsigned int*)&sVT[vdg + 1][vkp]      = ((unsigned)r.vc0.y << 16) | r.va0.y;
    *(unsigned int*)&sVT[vdg + 2][vkp]      = ((unsigned)r.vc0.z << 16) | r.va0.z;
    *(unsigned int*)&sVT[vdg + 3][vkp]      = ((unsigned)r.vc0.w << 16) | r.va0.w;
    *(unsigned int*)&sVT[vdg + 32 + 0][vkp] = ((unsigned)r.vc1.x << 16) | r.va1.x;
    *(unsigned int*)&sVT[vdg + 32 + 1][vkp] = ((unsigned)r.vc1.y << 16) | r.va1.y;
    *(unsigned int*)&sVT[vdg + 32 + 2][vkp] = ((unsigned)r.vc1.z << 16) | r.va1.z;
    *(unsigned int*)&sVT[vdg + 32 + 3][vkp] = ((unsigned)r.vc1.w << 16) | r.va1.w;
}

// pack 8 f32 P-values (p[i0..i0+7]) into one PA bf16x8 fragment, exchanging
// halves across the lane<32 / lane>=32 split via permlane32_swap.
__device__ __forceinline__ bf16x8 pack_pa(const f32x16& p, int i0)
{
    unsigned a0, a1, a2, a3;
    asm("v_cvt_pk_bf16_f32 %0, %1, %2" : "=v"(a0) : "v"(p[i0 + 0]), "v"(p[i0 + 1]));
    asm("v_cvt_pk_bf16_f32 %0, %1, %2" : "=v"(a1) : "v"(p[i0 + 2]), "v"(p[i0 + 3]));
    asm("v_cvt_pk_bf16_f32 %0, %1, %2" : "=v"(a2) : "v"(p[i0 + 4]), "v"(p[i0 + 5]));
    asm("v_cvt_pk_bf16_f32 %0, %1, %2" : "=v"(a3) : "v"(p[i0 + 6]), "v"(p[i0 + 7]));
    const u32x2 s02 = __builtin_amdgcn_permlane32_swap(a0, a2, false, false);
    const u32x2 s13 = __builtin_amdgcn_permlane32_swap(a1, a3, false, false);
    return __builtin_bit_cast(bf16x8, (u32x4){s02[0], s13[0], s02[1], s13[1]});
}

__device__ __forceinline__ void attn_tile(
    const __bf16 (*sK)[72], const __bf16 (*sVT)[72],
    const bf16x8* bQ, int lq, int hi,
    f32x16& O0, f32x16& O1, float& lsum)
{
    bf16x8 pa[4];
#pragma unroll
    for (int kb = 0; kb < 2; ++kb) {
        f32x16 p;
#pragma unroll
        for (int i = 0; i < 16; ++i) p[i] = 0.f;
        __builtin_amdgcn_s_setprio(1);
#pragma unroll
        for (int ks = 0; ks < 4; ++ks) {
            const bf16x8 aK = *(const bf16x8*)&sK[kb * 32 + lq][ks * 16 + hi * 8];
            p = __builtin_amdgcn_mfma_f32_32x32x16_bf16(aK, bQ[ks], p, 0, 0, 0);
        }
        __builtin_amdgcn_s_setprio(0);
        // scores already carry 0.125*log2e -> exp2 direct; running denominator.
        float ps = 0.f;
#pragma unroll
        for (int i = 0; i < 16; ++i) {
            p[i] = __builtin_amdgcn_exp2f(p[i]);
            ps += p[i];
        }
        lsum += ps;
        pa[kb * 2]     = pack_pa(p, 0);
        pa[kb * 2 + 1] = pack_pa(p, 8);
    }
    // PV: A = PA (regs), B = V^T (LDS). O[q][d], d = dblk*32 + (lane&31).
    __builtin_amdgcn_s_setprio(1);
#pragma unroll
    for (int ks = 0; ks < 4; ++ks) {
        const bf16x8 vb0 = *(const bf16x8*)&sVT[lq][ks * 16 + hi * 8];
        const bf16x8 vb1 = *(const bf16x8*)&sVT[32 + lq][ks * 16 + hi * 8];
        O0 = __builtin_amdgcn_mfma_f32_32x32x16_bf16(pa[ks], vb0, O0, 0, 0, 0);
        O1 = __builtin_amdgcn_mfma_f32_32x32x16_bf16(pa[ks], vb1, O1, 0, 0, 0);
    }
    __builtin_amdgcn_s_setprio(0);
}

__global__ __launch_bounds__(256, 4) void attn_kernel(
    const __bf16* __restrict__ qw, const __bf16* __restrict__ kw,
    const __bf16* __restrict__ vw, __bf16* __restrict__ ow)
{
    __shared__ __bf16 sK0[64][72], sVT0[64][72];
    __shared__ __bf16 sK1[64][72], sVT1[64][72];

    const int t    = threadIdx.x;
    const int lane = t & 63;
    const int w    = t >> 6;
    const int lq   = lane & 31;
    const int hi   = lane >> 5;

    const int bh  = blockIdx.y;
    const int b   = bh >> 5;
    const int h   = bh & 31;
    const int kvh = h >> 2;
    const int q0  = blockIdx.x * 128 + w * 32;   // this wave's 32 q-rows

    // Q fragments (pre-scaled by 0.125*log2e in gemm epilogue):
    // B[k=d][n=q]: n = lane&31, k = hi*8 + j within each 16-d step.
    bf16x8 bQ[4];
    {
        const __bf16* qrow = qw + (((size_t)b * S_ + q0 + lq) * H_ + h) * D_;
#pragma unroll
        for (int ks = 0; ks < 4; ++ks)
            bQ[ks] = *(const bf16x8*)(qrow + ks * 16 + hi * 8);
    }

    f32x16 O0, O1;
#pragma unroll
    for (int i = 0; i < 16; ++i) { O0[i] = 0.f; O1[i] = 0.f; }
    float lsum = 0.f;

    const __bf16* kbase = kw + ((size_t)b * S_ * HKV_ + kvh) * D_;
    const __bf16* vbase = vw + ((size_t)b * S_ * HKV_ + kvh) * D_;
    const int kkey = t >> 2,        kd  = (t & 3) * 16;
    const int vkp  = (t & 31) * 2,  vdg = (t >> 5) * 4;

    StageRegs sr;
    stage_load(sr, kbase, vbase, 0, kkey, kd, vkp, vdg);
    stage_write(sr, sK0, sVT0, kkey, kd, vkp, vdg);
    __syncthreads();

#pragma unroll 1
    for (int j0 = 0; j0 < S_; j0 += 128) {
        StageRegs nx;
        stage_load(nx, kbase, vbase, j0 + 64, kkey, kd, vkp, vdg);
        attn_tile(sK0, sVT0, bQ, lq, hi, O0, O1, lsum);
        stage_write(nx, sK1, sVT1, kkey, kd, vkp, vdg);
        __syncthreads();
        if (j0 + 128 < S_)
            stage_load(nx, kbase, vbase, j0 + 128, kkey, kd, vkp, vdg);
        attn_tile(sK1, sVT1, bQ, lq, hi, O0, O1, lsum);
        if (j0 + 128 < S_)
            stage_write(nx, sK0, sVT0, kkey, kd, vkp, vdg);
        __syncthreads();
    }

    // lane and lane^32 hold complementary key-halves of the denominator.
    lsum += __shfl_xor(lsum, 32);
    const float inv = 1.0f / lsum;

    // O C-layout: col = lane&31 = d-in-block, row q = (r&3)+8*(r>>2)+4*hi.
#pragma unroll
    for (int r = 0; r < 16; ++r) {
        const int   qr = (r & 3) + 8 * (r >> 2) + 4 * hi;
        const float li = __shfl(inv, qr);   // inv lives at lane == q
        __bf16* orow = ow + (((size_t)b * S_ + q0 + qr) * H_ + h) * D_;
        orow[lq]      = (__bf16)(O0[r] * li);
        orow[32 + lq] = (__bf16)(O1[r] * li);
    }
}

// ---------------------------------------------------------------------------
extern "C" void kernel_launch(void* const* d_in, const int* in_sizes, int n_in,
                              void* d_out, int out_size, void* d_ws, size_t ws_size,
                              hipStream_t stream)
{
    const float* x  = (const float*)d_in[0];
    const float* fc = (const float*)d_in[2];
    const float* fs = (const float*)d_in[3];
    const float* wq = (const float*)d_in[4];
    const float* wk = (const float*)d_in[5];
    const float* wv = (const float*)d_in[6];
    const float* wo = (const float*)d_in[7];
    const float* obias = (const float*)d_in[8];
    float* out = (float*)d_out;

    __bf16* ws  = (__bf16*)d_ws;
    __bf16* xb  = ws;                                    // 4096*2048
    __bf16* wT  = xb  + (size_t)4096 * 2048;             // 3072*2048 [wq^T|wk^T|wv^T]
    __bf16* woT = wT  + (size_t)3072 * 2048;             // 2048*2048
    __bf16* qb  = woT + (size_t)2048 * 2048;             // B,S,H,D
    __bf16* kb  = qb  + (size_t)B_ * S_ * H_ * D_;       // B,S,HKV,D
    __bf16* vb  = kb  + (size_t)B_ * S_ * HKV_ * D_;
    __bf16* obf = vb  + (size_t)B_ * S_ * HKV_ * D_;     // B,S,H,D

    convert_kernel<<<4096, 256, 0, stream>>>(x, xb, 4096 * 2048 / 8);
    transpose_convert_all_kernel<<<dim3(160, 64), 256, 0, stream>>>(
        wq, wk, wv, wo, wT, woT);

    gemm_qkv_kernel<<<dim3(24, 32), 256, 0, stream>>>(xb, wT, fc, fs, qb, kb, vb);

    attn_kernel<<<dim3(S_ / 128, B_ * H_), 256, 0, stream>>>(qb, kb, vb, obf);

    gemm_out_kernel<<<dim3(16, 32), 256, 0, stream>>>(obf, woT, obias, out);
}

// Round 4
// 378.929 us; speedup vs baseline: 1.3058x; 1.3058x over previous
//
#include <hip/hip_runtime.h>
#include <math.h>

#define B_    2
#define S_    2048
#define E_    2048
#define H_    32
#define HKV_  8
#define D_    64

typedef __bf16 bf16x8 __attribute__((ext_vector_type(8)));
typedef float  f32x4  __attribute__((ext_vector_type(4)));
typedef float  f32x16 __attribute__((ext_vector_type(16)));
typedef unsigned int u32x2 __attribute__((ext_vector_type(2)));
typedef unsigned int u32x4 __attribute__((ext_vector_type(4)));

#define GPTR(x) ((const __attribute__((address_space(1))) void*)(x))
#define LPTR(x) ((__attribute__((address_space(3))) void*)(x))

// 0.125 * log2(e): folded into Q so attention softmax is exp2-direct.
#define QK_SCALE_LOG2E 0.18033688011112042f

// ---------------------------------------------------------------------------
// fp32 -> bf16 flat convert (x)
// ---------------------------------------------------------------------------
__global__ __launch_bounds__(256) void convert_kernel(
    const float* __restrict__ in, __bf16* __restrict__ out, int n8)
{
    const int i = blockIdx.x * 256 + threadIdx.x;
    if (i >= n8) return;
    const float4 a = ((const float4*)in)[i * 2];
    const float4 b = ((const float4*)in)[i * 2 + 1];
    bf16x8 o;
    o[0] = (__bf16)a.x; o[1] = (__bf16)a.y; o[2] = (__bf16)a.z; o[3] = (__bf16)a.w;
    o[4] = (__bf16)b.x; o[5] = (__bf16)b.y; o[6] = (__bf16)b.z; o[7] = (__bf16)b.w;
    ((bf16x8*)out)[i] = o;
}

// ---------------------------------------------------------------------------
// All 4 weight transposes (fp32 (K,N) -> bf16 (N,K)) in ONE dispatch.
// K = 2048 for every weight. x-block range selects the source matrix.
// ---------------------------------------------------------------------------
__global__ __launch_bounds__(256) void transpose_convert_all_kernel(
    const float* __restrict__ wq, const float* __restrict__ wk,
    const float* __restrict__ wv, const float* __restrict__ wo,
    __bf16* __restrict__ wT, __bf16* __restrict__ woT)
{
    const float* in; __bf16* out; int N, xb;
    const int x = blockIdx.x;
    if (x < 64)      { in = wq; out = wT;                        N = 2048; xb = x; }
    else if (x < 80) { in = wk; out = wT + (size_t)2048 * 2048;  N = 512;  xb = x - 64; }
    else if (x < 96) { in = wv; out = wT + (size_t)2560 * 2048;  N = 512;  xb = x - 80; }
    else             { in = wo; out = woT;                       N = 2048; xb = x - 96; }
    const int K = 2048;

    __shared__ float tile[32][33];
    const int k0 = blockIdx.y * 32, n0 = xb * 32;
    const int r  = threadIdx.x >> 3;
    const int c4 = (threadIdx.x & 7) * 4;
    const float4 v = *(const float4*)&in[(size_t)(k0 + r) * N + n0 + c4];
    tile[r][c4 + 0] = v.x; tile[r][c4 + 1] = v.y;
    tile[r][c4 + 2] = v.z; tile[r][c4 + 3] = v.w;
    __syncthreads();
    ushort4 o;
    __bf16 h0 = (__bf16)tile[c4 + 0][r]; o.x = __builtin_bit_cast(unsigned short, h0);
    __bf16 h1 = (__bf16)tile[c4 + 1][r]; o.y = __builtin_bit_cast(unsigned short, h1);
    __bf16 h2 = (__bf16)tile[c4 + 2][r]; o.z = __builtin_bit_cast(unsigned short, h2);
    __bf16 h3 = (__bf16)tile[c4 + 3][r]; o.w = __builtin_bit_cast(unsigned short, h3);
    *(ushort4*)&out[(size_t)(n0 + r) * K + k0 + c4] = o;
}

// ---------------------------------------------------------------------------
// bf16 MFMA GEMM body (m97 structure) — unchanged
// ---------------------------------------------------------------------------
__device__ __forceinline__ void gemm_mfma_body(
    const __bf16* __restrict__ A, const __bf16* __restrict__ Bt,
    int m0, int n0, int K, __bf16* sA, __bf16* sB, f32x4 acc[4][4])
{
    const int t    = threadIdx.x;
    const int w    = t >> 6;
    const int lane = t & 63;
    const int col  = lane & 15;
    const int quad = lane >> 4;
    const int wrow = (w >> 1) * 64;
    const int wcol = (w & 1) * 64;

    const int row0 = t >> 3;
    const int c0   = t & 7;

    for (int k0 = 0; k0 < K; k0 += 64) {
#pragma unroll
        for (int it = 0; it < 4; ++it) {
            const int row  = it * 32 + row0;
            const int csrc = c0 ^ (row & 7);
            __builtin_amdgcn_global_load_lds(
                GPTR(A + (size_t)(m0 + row) * K + k0 + csrc * 8),
                LPTR(sA + (it * 256 + t) * 8), 16, 0, 0);
        }
#pragma unroll
        for (int it = 0; it < 4; ++it) {
            const int row  = it * 32 + row0;
            const int csrc = c0 ^ (row & 7);
            __builtin_amdgcn_global_load_lds(
                GPTR(Bt + (size_t)(n0 + row) * K + k0 + csrc * 8),
                LPTR(sB + (it * 256 + t) * 8), 16, 0, 0);
        }
        __syncthreads();

#pragma unroll
        for (int kk = 0; kk < 2; ++kk) {
            bf16x8 af[4], bfr[4];
#pragma unroll
            for (int i = 0; i < 4; ++i) {
                const int m = wrow + i * 16 + col;
                af[i] = *(const bf16x8*)&sA[m * 64 + (((kk * 4 + quad) ^ (m & 7)) * 8)];
            }
#pragma unroll
            for (int j = 0; j < 4; ++j) {
                const int n = wcol + j * 16 + col;
                bfr[j] = *(const bf16x8*)&sB[n * 64 + (((kk * 4 + quad) ^ (n & 7)) * 8)];
            }
#pragma unroll
            for (int i = 0; i < 4; ++i)
#pragma unroll
                for (int j = 0; j < 4; ++j)
                    acc[i][j] = __builtin_amdgcn_mfma_f32_16x16x32_bf16(
                        af[i], bfr[j], acc[i][j], 0, 0, 0);
        }
        __syncthreads();
    }
}

// ---------------------------------------------------------------------------
// QKV GEMM with FUSED RoPE in the epilogue (proven R3) + XCD-aware swizzle.
// ---------------------------------------------------------------------------
__global__ __launch_bounds__(256) void gemm_qkv_kernel(
    const __bf16* __restrict__ xb, const __bf16* __restrict__ wT,
    const float* __restrict__ fc, const float* __restrict__ fs,
    __bf16* __restrict__ qb, __bf16* __restrict__ kb, __bf16* __restrict__ vb)
{
    __shared__ __bf16 sA[128 * 64];
    __shared__ __bf16 sB[128 * 64];
    f32x4 acc[4][4];
#pragma unroll
    for (int i = 0; i < 4; ++i)
#pragma unroll
        for (int j = 0; j < 4; ++j) acc[i][j] = (f32x4){0.f, 0.f, 0.f, 0.f};

    // T1: XCD-aware swizzle. 768 blocks, 768 % 8 == 0 -> bijective.
    const int lin     = blockIdx.y * 24 + blockIdx.x;
    const int logical = (lin & 7) * 96 + (lin >> 3);
    const int bx      = logical % 24;
    const int m0      = (logical / 24) * 128;

    gemm_mfma_body(xb, wT, m0, bx * 128, E_, sA, sB, acc);

    __bf16* Cp; int ldc, nb;
    if (bx < 16)      { Cp = qb; ldc = H_ * D_;   nb = bx * 128; }
    else if (bx < 20) { Cp = kb; ldc = HKV_ * D_; nb = (bx - 16) * 128; }
    else              { Cp = vb; ldc = HKV_ * D_; nb = (bx - 20) * 128; }

    const bool  doRope = (bx < 20);
    const float qsc    = (bx < 16) ? QK_SCALE_LOG2E : 1.0f;

    const int lane = threadIdx.x & 63;
    const int col  = lane & 15;
    const int quad = lane >> 4;
    const int wrow = ((threadIdx.x >> 6) >> 1) * 64;
    const int wcol = ((threadIdx.x >> 6) & 1) * 64;
#pragma unroll
    for (int i = 0; i < 4; ++i)
#pragma unroll
        for (int j = 0; j < 4; ++j)
#pragma unroll
            for (int r = 0; r < 4; ++r) {
                const int m = m0 + wrow + i * 16 + quad * 4 + r;
                const int n = nb + wcol + j * 16 + col;
                float val = acc[i][j][r] * qsc;
                if (doRope) {
                    const int   s    = m & (S_ - 1);
                    const int   pair = (n & 63) >> 1;
                    const float c    = fc[s * 32 + pair];
                    const float sn   = fs[s * 32 + pair];
                    const float oth  = __shfl_xor(val, 1);
                    // even lane: val=x0, oth=x1 -> x0*c - x1*sn
                    // odd lane:  val=x1, oth=x0 -> x0*sn + x1*c
                    val = (lane & 1) ? (oth * sn + val * c)
                                     : (val * c - oth * sn);
                }
                Cp[(size_t)m * ldc + n] = (__bf16)val;
            }
}

__global__ __launch_bounds__(256) void gemm_out_kernel(
    const __bf16* __restrict__ ob, const __bf16* __restrict__ woT,
    const float* __restrict__ bias, float* __restrict__ out)
{
    __shared__ __bf16 sA[128 * 64];
    __shared__ __bf16 sB[128 * 64];
    f32x4 acc[4][4];
#pragma unroll
    for (int i = 0; i < 4; ++i)
#pragma unroll
        for (int j = 0; j < 4; ++j) acc[i][j] = (f32x4){0.f, 0.f, 0.f, 0.f};

    // T1: XCD-aware swizzle. 512 blocks, 512 % 8 == 0 -> bijective.
    const int lin     = blockIdx.y * 16 + blockIdx.x;
    const int logical = (lin & 7) * 64 + (lin >> 3);
    const int n0      = (logical % 16) * 128;
    const int m0      = (logical / 16) * 128;

    gemm_mfma_body(ob, woT, m0, n0, H_ * D_, sA, sB, acc);

    const int lane = threadIdx.x & 63;
    const int col  = lane & 15;
    const int quad = lane >> 4;
    const int wrow = ((threadIdx.x >> 6) >> 1) * 64;
    const int wcol = ((threadIdx.x >> 6) & 1) * 64;
#pragma unroll
    for (int i = 0; i < 4; ++i)
#pragma unroll
        for (int j = 0; j < 4; ++j)
#pragma unroll
            for (int r = 0; r < 4; ++r) {
                const int m = m0 + wrow + i * 16 + quad * 4 + r;
                const int n = n0 + wcol + j * 16 + col;
                out[(size_t)m * E_ + n] = acc[i][j][r] + bias[n];
            }
}

// ---------------------------------------------------------------------------
// MFMA flash attention v3 (m214-style): swapped QK^T on 32x32x16 MFMA.
// Per block: 4 waves x 32 q-rows = 128 q. A=K, B=Q -> lane holds P[q][16 keys]
// in registers; exp2-direct (scale folded into Q); in-register P->bf16 via
// v_cvt_pk_bf16_f32 + __builtin_amdgcn_permlane32_swap; PV from PA regs.
// K/V^T double-buffered in LDS, reg-staged async, ONE barrier per 64-key tile.
// launch_bounds(256,3): proven no-spill point (84 VGPR). (256,4) forces the
// allocator under the kernel's ~130 VGPR+AGPR demand -> 287 MB scratch spill
// (R3: 225 µs). Do not raise without cutting register demand first.
// ---------------------------------------------------------------------------
struct StageRegs {
    bf16x8  k0, k1;
    ushort4 va0, vc0, va1, vc1;
};

__device__ __forceinline__ void stage_load(
    StageRegs& r, const __bf16* kbase, const __bf16* vbase, int j0,
    int kkey, int kd, int vkp, int vdg)
{
    const int KSTR = HKV_ * D_;   // 512
    const __bf16* kr = kbase + (size_t)(j0 + kkey) * KSTR + kd;
    r.k0 = ((const bf16x8*)kr)[0];
    r.k1 = ((const bf16x8*)kr)[1];
    const __bf16* v0 = vbase + (size_t)(j0 + vkp) * KSTR + vdg;
    r.va0 = *(const ushort4*)(v0);
    r.vc0 = *(const ushort4*)(v0 + KSTR);
    r.va1 = *(const ushort4*)(v0 + 32);
    r.vc1 = *(const ushort4*)(v0 + KSTR + 32);
}

__device__ __forceinline__ void stage_write(
    const StageRegs& r, __bf16 (*sK)[72], __bf16 (*sVT)[72],
    int kkey, int kd, int vkp, int vdg)
{
    *(bf16x8*)&sK[kkey][kd]     = r.k0;
    *(bf16x8*)&sK[kkey][kd + 8] = r.k1;
    *(unsigned int*)&sVT[vdg + 0][vkp]      = ((unsigned)r.vc0.x << 16) | r.va0.x;
    *(unsigned int*)&sVT[vdg + 1][vkp]      = ((unsigned)r.vc0.y << 16) | r.va0.y;
    *(unsigned int*)&sVT[vdg + 2][vkp]      = ((unsigned)r.vc0.z << 16) | r.va0.z;
    *(unsigned int*)&sVT[vdg + 3][vkp]      = ((unsigned)r.vc0.w << 16) | r.va0.w;
    *(unsigned int*)&sVT[vdg + 32 + 0][vkp] = ((unsigned)r.vc1.x << 16) | r.va1.x;
    *(unsigned int*)&sVT[vdg + 32 + 1][vkp] = ((unsigned)r.vc1.y << 16) | r.va1.y;
    *(unsigned int*)&sVT[vdg + 32 + 2][vkp] = ((unsigned)r.vc1.z << 16) | r.va1.z;
    *(unsigned int*)&sVT[vdg + 32 + 3][vkp] = ((unsigned)r.vc1.w << 16) | r.va1.w;
}

// pack 8 f32 P-values (p[i0..i0+7]) into one PA bf16x8 fragment, exchanging
// halves across the lane<32 / lane>=32 split via permlane32_swap.
__device__ __forceinline__ bf16x8 pack_pa(const f32x16& p, int i0)
{
    unsigned a0, a1, a2, a3;
    asm("v_cvt_pk_bf16_f32 %0, %1, %2" : "=v"(a0) : "v"(p[i0 + 0]), "v"(p[i0 + 1]));
    asm("v_cvt_pk_bf16_f32 %0, %1, %2" : "=v"(a1) : "v"(p[i0 + 2]), "v"(p[i0 + 3]));
    asm("v_cvt_pk_bf16_f32 %0, %1, %2" : "=v"(a2) : "v"(p[i0 + 4]), "v"(p[i0 + 5]));
    asm("v_cvt_pk_bf16_f32 %0, %1, %2" : "=v"(a3) : "v"(p[i0 + 6]), "v"(p[i0 + 7]));
    const u32x2 s02 = __builtin_amdgcn_permlane32_swap(a0, a2, false, false);
    const u32x2 s13 = __builtin_amdgcn_permlane32_swap(a1, a3, false, false);
    return __builtin_bit_cast(bf16x8, (u32x4){s02[0], s13[0], s02[1], s13[1]});
}

__device__ __forceinline__ void attn_tile(
    const __bf16 (*sK)[72], const __bf16 (*sVT)[72],
    const bf16x8* bQ, int lq, int hi,
    f32x16& O0, f32x16& O1, float& lsum)
{
    bf16x8 pa[4];
#pragma unroll
    for (int kb = 0; kb < 2; ++kb) {
        f32x16 p;
#pragma unroll
        for (int i = 0; i < 16; ++i) p[i] = 0.f;
        __builtin_amdgcn_s_setprio(1);
#pragma unroll
        for (int ks = 0; ks < 4; ++ks) {
            const bf16x8 aK = *(const bf16x8*)&sK[kb * 32 + lq][ks * 16 + hi * 8];
            p = __builtin_amdgcn_mfma_f32_32x32x16_bf16(aK, bQ[ks], p, 0, 0, 0);
        }
        __builtin_amdgcn_s_setprio(0);
        // scores already carry 0.125*log2e -> exp2 direct; running denominator.
        float ps = 0.f;
#pragma unroll
        for (int i = 0; i < 16; ++i) {
            p[i] = __builtin_amdgcn_exp2f(p[i]);
            ps += p[i];
        }
        lsum += ps;
        pa[kb * 2]     = pack_pa(p, 0);
        pa[kb * 2 + 1] = pack_pa(p, 8);
    }
    // PV: A = PA (regs), B = V^T (LDS). O[q][d], d = dblk*32 + (lane&31).
    __builtin_amdgcn_s_setprio(1);
#pragma unroll
    for (int ks = 0; ks < 4; ++ks) {
        const bf16x8 vb0 = *(const bf16x8*)&sVT[lq][ks * 16 + hi * 8];
        const bf16x8 vb1 = *(const bf16x8*)&sVT[32 + lq][ks * 16 + hi * 8];
        O0 = __builtin_amdgcn_mfma_f32_32x32x16_bf16(pa[ks], vb0, O0, 0, 0, 0);
        O1 = __builtin_amdgcn_mfma_f32_32x32x16_bf16(pa[ks], vb1, O1, 0, 0, 0);
    }
    __builtin_amdgcn_s_setprio(0);
}

__global__ __launch_bounds__(256, 3) void attn_kernel(
    const __bf16* __restrict__ qw, const __bf16* __restrict__ kw,
    const __bf16* __restrict__ vw, __bf16* __restrict__ ow)
{
    __shared__ __bf16 sK0[64][72], sVT0[64][72];
    __shared__ __bf16 sK1[64][72], sVT1[64][72];

    const int t    = threadIdx.x;
    const int lane = t & 63;
    const int w    = t >> 6;
    const int lq   = lane & 31;
    const int hi   = lane >> 5;

    const int bh  = blockIdx.y;
    const int b   = bh >> 5;
    const int h   = bh & 31;
    const int kvh = h >> 2;
    const int q0  = blockIdx.x * 128 + w * 32;   // this wave's 32 q-rows

    // Q fragments (pre-scaled by 0.125*log2e in gemm epilogue):
    // B[k=d][n=q]: n = lane&31, k = hi*8 + j within each 16-d step.
    bf16x8 bQ[4];
    {
        const __bf16* qrow = qw + (((size_t)b * S_ + q0 + lq) * H_ + h) * D_;
#pragma unroll
        for (int ks = 0; ks < 4; ++ks)
            bQ[ks] = *(const bf16x8*)(qrow + ks * 16 + hi * 8);
    }

    f32x16 O0, O1;
#pragma unroll
    for (int i = 0; i < 16; ++i) { O0[i] = 0.f; O1[i] = 0.f; }
    float lsum = 0.f;

    const __bf16* kbase = kw + ((size_t)b * S_ * HKV_ + kvh) * D_;
    const __bf16* vbase = vw + ((size_t)b * S_ * HKV_ + kvh) * D_;
    const int kkey = t >> 2,        kd  = (t & 3) * 16;
    const int vkp  = (t & 31) * 2,  vdg = (t >> 5) * 4;

    StageRegs sr;
    stage_load(sr, kbase, vbase, 0, kkey, kd, vkp, vdg);
    stage_write(sr, sK0, sVT0, kkey, kd, vkp, vdg);
    __syncthreads();

#pragma unroll 1
    for (int j0 = 0; j0 < S_; j0 += 128) {
        StageRegs nx;
        stage_load(nx, kbase, vbase, j0 + 64, kkey, kd, vkp, vdg);
        attn_tile(sK0, sVT0, bQ, lq, hi, O0, O1, lsum);
        stage_write(nx, sK1, sVT1, kkey, kd, vkp, vdg);
        __syncthreads();
        if (j0 + 128 < S_)
            stage_load(nx, kbase, vbase, j0 + 128, kkey, kd, vkp, vdg);
        attn_tile(sK1, sVT1, bQ, lq, hi, O0, O1, lsum);
        if (j0 + 128 < S_)
            stage_write(nx, sK0, sVT0, kkey, kd, vkp, vdg);
        __syncthreads();
    }

    // lane and lane^32 hold complementary key-halves of the denominator.
    lsum += __shfl_xor(lsum, 32);
    const float inv = 1.0f / lsum;

    // O C-layout: col = lane&31 = d-in-block, row q = (r&3)+8*(r>>2)+4*hi.
#pragma unroll
    for (int r = 0; r < 16; ++r) {
        const int   qr = (r & 3) + 8 * (r >> 2) + 4 * hi;
        const float li = __shfl(inv, qr);   // inv lives at lane == q
        __bf16* orow = ow + (((size_t)b * S_ + q0 + qr) * H_ + h) * D_;
        orow[lq]      = (__bf16)(O0[r] * li);
        orow[32 + lq] = (__bf16)(O1[r] * li);
    }
}

// ---------------------------------------------------------------------------
extern "C" void kernel_launch(void* const* d_in, const int* in_sizes, int n_in,
                              void* d_out, int out_size, void* d_ws, size_t ws_size,
                              hipStream_t stream)
{
    const float* x  = (const float*)d_in[0];
    const float* fc = (const float*)d_in[2];
    const float* fs = (const float*)d_in[3];
    const float* wq = (const float*)d_in[4];
    const float* wk = (const float*)d_in[5];
    const float* wv = (const float*)d_in[6];
    const float* wo = (const float*)d_in[7];
    const float* obias = (const float*)d_in[8];
    float* out = (float*)d_out;

    __bf16* ws  = (__bf16*)d_ws;
    __bf16* xb  = ws;                                    // 4096*2048
    __bf16* wT  = xb  + (size_t)4096 * 2048;             // 3072*2048 [wq^T|wk^T|wv^T]
    __bf16* woT = wT  + (size_t)3072 * 2048;             // 2048*2048
    __bf16* qb  = woT + (size_t)2048 * 2048;             // B,S,H,D
    __bf16* kb  = qb  + (size_t)B_ * S_ * H_ * D_;       // B,S,HKV,D
    __bf16* vb  = kb  + (size_t)B_ * S_ * HKV_ * D_;
    __bf16* obf = vb  + (size_t)B_ * S_ * HKV_ * D_;     // B,S,H,D

    convert_kernel<<<4096, 256, 0, stream>>>(x, xb, 4096 * 2048 / 8);
    transpose_convert_all_kernel<<<dim3(160, 64), 256, 0, stream>>>(
        wq, wk, wv, wo, wT, woT);

    gemm_qkv_kernel<<<dim3(24, 32), 256, 0, stream>>>(xb, wT, fc, fs, qb, kb, vb);

    attn_kernel<<<dim3(S_ / 128, B_ * H_), 256, 0, stream>>>(qb, kb, vb, obf);

    gemm_out_kernel<<<dim3(16, 32), 256, 0, stream>>>(obf, woT, obias, out);
}

// Round 5
// 359.257 us; speedup vs baseline: 1.3774x; 1.0548x over previous
//
#include <hip/hip_runtime.h>
#include <math.h>

#define B_    2
#define S_    2048
#define E_    2048
#define H_    32
#define HKV_  8
#define D_    64

typedef __bf16 bf16x8 __attribute__((ext_vector_type(8)));
typedef float  f32x4  __attribute__((ext_vector_type(4)));
typedef float  f32x16 __attribute__((ext_vector_type(16)));
typedef unsigned int u32x2 __attribute__((ext_vector_type(2)));
typedef unsigned int u32x4 __attribute__((ext_vector_type(4)));

#define GPTR(x) ((const __attribute__((address_space(1))) void*)(x))
#define LPTR(x) ((__attribute__((address_space(3))) void*)(x))

// 0.125 * log2(e): folded into Q so attention softmax is exp2-direct.
#define QK_SCALE_LOG2E 0.18033688011112042f

// ---------------------------------------------------------------------------
// fp32 -> bf16 flat convert (x)
// ---------------------------------------------------------------------------
__global__ __launch_bounds__(256) void convert_kernel(
    const float* __restrict__ in, __bf16* __restrict__ out, int n8)
{
    const int i = blockIdx.x * 256 + threadIdx.x;
    if (i >= n8) return;
    const float4 a = ((const float4*)in)[i * 2];
    const float4 b = ((const float4*)in)[i * 2 + 1];
    bf16x8 o;
    o[0] = (__bf16)a.x; o[1] = (__bf16)a.y; o[2] = (__bf16)a.z; o[3] = (__bf16)a.w;
    o[4] = (__bf16)b.x; o[5] = (__bf16)b.y; o[6] = (__bf16)b.z; o[7] = (__bf16)b.w;
    ((bf16x8*)out)[i] = o;
}

// ---------------------------------------------------------------------------
// All 4 weight transposes (fp32 (K,N) -> bf16 (N,K)) in ONE dispatch.
// ---------------------------------------------------------------------------
__global__ __launch_bounds__(256) void transpose_convert_all_kernel(
    const float* __restrict__ wq, const float* __restrict__ wk,
    const float* __restrict__ wv, const float* __restrict__ wo,
    __bf16* __restrict__ wT, __bf16* __restrict__ woT)
{
    const float* in; __bf16* out; int N, xb;
    const int x = blockIdx.x;
    if (x < 64)      { in = wq; out = wT;                        N = 2048; xb = x; }
    else if (x < 80) { in = wk; out = wT + (size_t)2048 * 2048;  N = 512;  xb = x - 64; }
    else if (x < 96) { in = wv; out = wT + (size_t)2560 * 2048;  N = 512;  xb = x - 80; }
    else             { in = wo; out = woT;                       N = 2048; xb = x - 96; }
    const int K = 2048;

    __shared__ float tile[32][33];
    const int k0 = blockIdx.y * 32, n0 = xb * 32;
    const int r  = threadIdx.x >> 3;
    const int c4 = (threadIdx.x & 7) * 4;
    const float4 v = *(const float4*)&in[(size_t)(k0 + r) * N + n0 + c4];
    tile[r][c4 + 0] = v.x; tile[r][c4 + 1] = v.y;
    tile[r][c4 + 2] = v.z; tile[r][c4 + 3] = v.w;
    __syncthreads();
    ushort4 o;
    __bf16 h0 = (__bf16)tile[c4 + 0][r]; o.x = __builtin_bit_cast(unsigned short, h0);
    __bf16 h1 = (__bf16)tile[c4 + 1][r]; o.y = __builtin_bit_cast(unsigned short, h1);
    __bf16 h2 = (__bf16)tile[c4 + 2][r]; o.z = __builtin_bit_cast(unsigned short, h2);
    __bf16 h3 = (__bf16)tile[c4 + 3][r]; o.w = __builtin_bit_cast(unsigned short, h3);
    *(ushort4*)&out[(size_t)(n0 + r) * K + k0 + c4] = o;
}

// ---------------------------------------------------------------------------
// Pipelined GEMM (T2+T3+T4+T5): 512 threads = 8 waves (2M x 4N), BM=256,
// BK=32, 4-slot LDS ring, counted vmcnt (never 0 in main loop).
// Phase(T): vmcnt(2L); s_barrier; stage(T+3); ds_read 12 frags(T); MFMA x32.
// Race-freedom: slot (T+3)&3 last read in phase T-1, all waves passed this
// phase's barrier after those reads completed (reads complete before each
// wave's MFMAs). Readiness: at phase T's vmcnt(2L), the only loads older
// than the newest 2L are tile T's -> complete; barrier makes them visible
// cross-wave. LDS swizzle: chunk ^= (row>>1)&3 on BOTH source (pre-swizzled
// global addr; global_load_lds dest stays linear) and ds_read -> uniform
// 2 lanes/bank-slot (free).
// ---------------------------------------------------------------------------
template<int BN> struct PG {
    static constexpr int BM     = 256;
    static constexpr int BK     = 32;
    static constexpr int ASLOT  = BM * BK;       // elems (16 KB)
    static constexpr int BSLOT  = BN * BK;
    static constexpr int SLOT   = ASLOT + BSLOT;
    static constexpr int BINSTR = BN / 128;      // gload instrs for B per tile
    static constexpr int L      = 2 + BINSTR;    // gloads per thread per tile
    static constexpr int NJ     = BN / 64;       // B-frags per wave
};

template<int BN>
__device__ __forceinline__ void stage_tile(
    const __bf16* __restrict__ A, const __bf16* __restrict__ Bt,
    int m0, int n0, int K, int T, __bf16* sl, int t, int wbase)
{
    using G = PG<BN>;
    const int k0   = T * G::BK;
    const int rsub = t >> 2;        // 0..127
    const int cp   = t & 3;         // physical 16B chunk within 64B row
#pragma unroll
    for (int g = 0; g < 2; ++g) {
        const int row = g * 128 + rsub;
        const int cl  = cp ^ ((row >> 1) & 3);     // pre-swizzled source chunk
        __builtin_amdgcn_global_load_lds(
            GPTR(A + (size_t)(m0 + row) * K + k0 + cl * 8),
            LPTR(sl + (g * 512 + wbase) * 8), 16, 0, 0);
    }
#pragma unroll
    for (int g = 0; g < G::BINSTR; ++g) {
        const int row = g * 128 + rsub;
        const int cl  = cp ^ ((row >> 1) & 3);
        __builtin_amdgcn_global_load_lds(
            GPTR(Bt + (size_t)(n0 + row) * K + k0 + cl * 8),
            LPTR(sl + G::ASLOT + (g * 512 + wbase) * 8), 16, 0, 0);
    }
}

template<int BN>
__device__ __forceinline__ void compute_tile(
    const __bf16* sl, int wrow, int wcol, int col, int quad,
    f32x4 acc[8][PG<BN>::NJ])
{
    using G = PG<BN>;
    bf16x8 af[8], bfr[G::NJ];
#pragma unroll
    for (int i = 0; i < 8; ++i) {
        const int m = wrow + i * 16 + col;
        af[i] = *(const bf16x8*)&sl[m * 32 + ((quad ^ ((m >> 1) & 3)) * 8)];
    }
#pragma unroll
    for (int j = 0; j < G::NJ; ++j) {
        const int n = wcol + j * 16 + col;
        bfr[j] = *(const bf16x8*)&sl[G::ASLOT + n * 32 + ((quad ^ ((n >> 1) & 3)) * 8)];
    }
    __builtin_amdgcn_s_setprio(1);
#pragma unroll
    for (int i = 0; i < 8; ++i)
#pragma unroll
        for (int j = 0; j < G::NJ; ++j)
            acc[i][j] = __builtin_amdgcn_mfma_f32_16x16x32_bf16(
                af[i], bfr[j], acc[i][j], 0, 0, 0);
    __builtin_amdgcn_s_setprio(0);
}

template<int BN>
__device__ __forceinline__ void gemm_pipe_body(
    const __bf16* __restrict__ A, const __bf16* __restrict__ Bt,
    int m0, int n0, int K, __bf16* sL, f32x4 acc[8][PG<BN>::NJ])
{
    using G = PG<BN>;
    const int t     = threadIdx.x;
    const int wbase = t & ~63;
    const int lane  = t & 63;
    const int col   = lane & 15;
    const int quad  = lane >> 4;
    const int w     = t >> 6;
    const int wrow  = (w >> 2) * 128;
    const int wcol  = (w & 3) * (BN / 4);
    const int NT    = K / G::BK;

    stage_tile<BN>(A, Bt, m0, n0, K, 0, sL + 0 * G::SLOT, t, wbase);
    stage_tile<BN>(A, Bt, m0, n0, K, 1, sL + 1 * G::SLOT, t, wbase);
    stage_tile<BN>(A, Bt, m0, n0, K, 2, sL + 2 * G::SLOT, t, wbase);

    int T = 0;
#pragma unroll 1
    for (; T < NT - 3; ++T) {
        asm volatile("s_waitcnt vmcnt(%0)" :: "n"(2 * G::L) : "memory");
        __builtin_amdgcn_s_barrier();
        stage_tile<BN>(A, Bt, m0, n0, K, T + 3, sL + ((T + 3) & 3) * G::SLOT, t, wbase);
        compute_tile<BN>(sL + (T & 3) * G::SLOT, wrow, wcol, col, quad, acc);
    }
    asm volatile("s_waitcnt vmcnt(%0)" :: "n"(2 * G::L) : "memory");
    __builtin_amdgcn_s_barrier();
    compute_tile<BN>(sL + (T & 3) * G::SLOT, wrow, wcol, col, quad, acc); ++T;
    asm volatile("s_waitcnt vmcnt(%0)" :: "n"(G::L) : "memory");
    __builtin_amdgcn_s_barrier();
    compute_tile<BN>(sL + (T & 3) * G::SLOT, wrow, wcol, col, quad, acc); ++T;
    asm volatile("s_waitcnt vmcnt(0)" ::: "memory");
    __builtin_amdgcn_s_barrier();
    compute_tile<BN>(sL + (T & 3) * G::SLOT, wrow, wcol, col, quad, acc);
}

// ---------------------------------------------------------------------------
// QKV GEMM (BM=256, BN=256): 16x12 = 192 blocks, fused RoPE/scale epilogue.
// ---------------------------------------------------------------------------
__global__ __launch_bounds__(512, 2) void gemm_qkv_kernel(
    const __bf16* __restrict__ xb, const __bf16* __restrict__ wT,
    const float* __restrict__ fc, const float* __restrict__ fs,
    __bf16* __restrict__ qb, __bf16* __restrict__ kb, __bf16* __restrict__ vb)
{
    __shared__ __bf16 sL[4 * PG<256>::SLOT];   // 128 KiB
    f32x4 acc[8][4];
#pragma unroll
    for (int i = 0; i < 8; ++i)
#pragma unroll
        for (int j = 0; j < 4; ++j) acc[i][j] = (f32x4){0.f, 0.f, 0.f, 0.f};

    // T1: bijective XCD swizzle over 192 blocks (192 % 8 == 0).
    const int lin     = blockIdx.x;
    const int logical = (lin & 7) * 24 + (lin >> 3);
    const int bx      = logical % 12;          // col-tile: 0-7 Q, 8-9 K, 10-11 V
    const int m0      = (logical / 12) * 256;
    const int n0      = bx * 256;

    gemm_pipe_body<256>(xb, wT, m0, n0, E_, sL, acc);

    __bf16* Cp; int ldc, base;
    if (bx < 8)       { Cp = qb; ldc = H_ * D_;   base = 0;    }
    else if (bx < 10) { Cp = kb; ldc = HKV_ * D_; base = 2048; }
    else              { Cp = vb; ldc = HKV_ * D_; base = 2560; }
    const bool  doRope = (bx < 10);
    const float qsc    = (bx < 8) ? QK_SCALE_LOG2E : 1.0f;

    const int t    = threadIdx.x;
    const int lane = t & 63;
    const int col  = lane & 15;
    const int quad = lane >> 4;
    const int w    = t >> 6;
    const int wrow = (w >> 2) * 128;
    const int wcol = (w & 3) * 64;
#pragma unroll
    for (int i = 0; i < 8; ++i)
#pragma unroll
        for (int j = 0; j < 4; ++j)
#pragma unroll
            for (int r = 0; r < 4; ++r) {
                const int m  = m0 + wrow + i * 16 + quad * 4 + r;
                const int ng = n0 + wcol + j * 16 + col;
                float val = acc[i][j][r] * qsc;
                if (doRope) {
                    const int   s    = m & (S_ - 1);
                    const int   pair = (ng & 63) >> 1;
                    const float c    = fc[s * 32 + pair];
                    const float sn   = fs[s * 32 + pair];
                    const float oth  = __shfl_xor(val, 1);
                    val = (lane & 1) ? (oth * sn + val * c)
                                     : (val * c - oth * sn);
                }
                Cp[(size_t)m * ldc + (ng - base)] = (__bf16)val;
            }
}

// ---------------------------------------------------------------------------
// Output GEMM (BM=256, BN=128): 16x16 = 256 blocks (full CU fill), bias.
// ---------------------------------------------------------------------------
__global__ __launch_bounds__(512, 2) void gemm_out_kernel(
    const __bf16* __restrict__ ob, const __bf16* __restrict__ woT,
    const float* __restrict__ bias, float* __restrict__ out)
{
    __shared__ __bf16 sL[4 * PG<128>::SLOT];   // 96 KiB
    f32x4 acc[8][2];
#pragma unroll
    for (int i = 0; i < 8; ++i)
#pragma unroll
        for (int j = 0; j < 2; ++j) acc[i][j] = (f32x4){0.f, 0.f, 0.f, 0.f};

    // T1: bijective XCD swizzle over 256 blocks.
    const int lin     = blockIdx.x;
    const int logical = (lin & 7) * 32 + (lin >> 3);
    const int n0      = (logical % 16) * 128;
    const int m0      = (logical / 16) * 256;

    gemm_pipe_body<128>(ob, woT, m0, n0, H_ * D_, sL, acc);

    const int t    = threadIdx.x;
    const int lane = t & 63;
    const int col  = lane & 15;
    const int quad = lane >> 4;
    const int w    = t >> 6;
    const int wrow = (w >> 2) * 128;
    const int wcol = (w & 3) * 32;
#pragma unroll
    for (int i = 0; i < 8; ++i)
#pragma unroll
        for (int j = 0; j < 2; ++j)
#pragma unroll
            for (int r = 0; r < 4; ++r) {
                const int m = m0 + wrow + i * 16 + quad * 4 + r;
                const int n = n0 + wcol + j * 16 + col;
                out[(size_t)m * E_ + n] = acc[i][j][r] + bias[n];
            }
}

// ---------------------------------------------------------------------------
// MFMA flash attention v3 (unchanged from R4: 110.5 µs, 84 VGPR, no spill).
// launch_bounds(256,3): proven no-spill point. (256,4) -> 287 MB scratch (R3).
// ---------------------------------------------------------------------------
struct StageRegs {
    bf16x8  k0, k1;
    ushort4 va0, vc0, va1, vc1;
};

__device__ __forceinline__ void stage_load(
    StageRegs& r, const __bf16* kbase, const __bf16* vbase, int j0,
    int kkey, int kd, int vkp, int vdg)
{
    const int KSTR = HKV_ * D_;   // 512
    const __bf16* kr = kbase + (size_t)(j0 + kkey) * KSTR + kd;
    r.k0 = ((const bf16x8*)kr)[0];
    r.k1 = ((const bf16x8*)kr)[1];
    const __bf16* v0 = vbase + (size_t)(j0 + vkp) * KSTR + vdg;
    r.va0 = *(const ushort4*)(v0);
    r.vc0 = *(const ushort4*)(v0 + KSTR);
    r.va1 = *(const ushort4*)(v0 + 32);
    r.vc1 = *(const ushort4*)(v0 + KSTR + 32);
}

__device__ __forceinline__ void stage_write(
    const StageRegs& r, __bf16 (*sK)[72], __bf16 (*sVT)[72],
    int kkey, int kd, int vkp, int vdg)
{
    *(bf16x8*)&sK[kkey][kd]     = r.k0;
    *(bf16x8*)&sK[kkey][kd + 8] = r.k1;
    *(unsigned int*)&sVT[vdg + 0][vkp]      = ((unsigned)r.vc0.x << 16) | r.va0.x;
    *(unsigned int*)&sVT[vdg + 1][vkp]      = ((unsigned)r.vc0.y << 16) | r.va0.y;
    *(unsigned int*)&sVT[vdg + 2][vkp]      = ((unsigned)r.vc0.z << 16) | r.va0.z;
    *(unsigned int*)&sVT[vdg + 3][vkp]      = ((unsigned)r.vc0.w << 16) | r.va0.w;
    *(unsigned int*)&sVT[vdg + 32 + 0][vkp] = ((unsigned)r.vc1.x << 16) | r.va1.x;
    *(unsigned int*)&sVT[vdg + 32 + 1][vkp] = ((unsigned)r.vc1.y << 16) | r.va1.y;
    *(unsigned int*)&sVT[vdg + 32 + 2][vkp] = ((unsigned)r.vc1.z << 16) | r.va1.z;
    *(unsigned int*)&sVT[vdg + 32 + 3][vkp] = ((unsigned)r.vc1.w << 16) | r.va1.w;
}

__device__ __forceinline__ bf16x8 pack_pa(const f32x16& p, int i0)
{
    unsigned a0, a1, a2, a3;
    asm("v_cvt_pk_bf16_f32 %0, %1, %2" : "=v"(a0) : "v"(p[i0 + 0]), "v"(p[i0 + 1]));
    asm("v_cvt_pk_bf16_f32 %0, %1, %2" : "=v"(a1) : "v"(p[i0 + 2]), "v"(p[i0 + 3]));
    asm("v_cvt_pk_bf16_f32 %0, %1, %2" : "=v"(a2) : "v"(p[i0 + 4]), "v"(p[i0 + 5]));
    asm("v_cvt_pk_bf16_f32 %0, %1, %2" : "=v"(a3) : "v"(p[i0 + 6]), "v"(p[i0 + 7]));
    const u32x2 s02 = __builtin_amdgcn_permlane32_swap(a0, a2, false, false);
    const u32x2 s13 = __builtin_amdgcn_permlane32_swap(a1, a3, false, false);
    return __builtin_bit_cast(bf16x8, (u32x4){s02[0], s13[0], s02[1], s13[1]});
}

__device__ __forceinline__ void attn_tile(
    const __bf16 (*sK)[72], const __bf16 (*sVT)[72],
    const bf16x8* bQ, int lq, int hi,
    f32x16& O0, f32x16& O1, float& lsum)
{
    bf16x8 pa[4];
#pragma unroll
    for (int kb = 0; kb < 2; ++kb) {
        f32x16 p;
#pragma unroll
        for (int i = 0; i < 16; ++i) p[i] = 0.f;
        __builtin_amdgcn_s_setprio(1);
#pragma unroll
        for (int ks = 0; ks < 4; ++ks) {
            const bf16x8 aK = *(const bf16x8*)&sK[kb * 32 + lq][ks * 16 + hi * 8];
            p = __builtin_amdgcn_mfma_f32_32x32x16_bf16(aK, bQ[ks], p, 0, 0, 0);
        }
        __builtin_amdgcn_s_setprio(0);
        float ps = 0.f;
#pragma unroll
        for (int i = 0; i < 16; ++i) {
            p[i] = __builtin_amdgcn_exp2f(p[i]);
            ps += p[i];
        }
        lsum += ps;
        pa[kb * 2]     = pack_pa(p, 0);
        pa[kb * 2 + 1] = pack_pa(p, 8);
    }
    __builtin_amdgcn_s_setprio(1);
#pragma unroll
    for (int ks = 0; ks < 4; ++ks) {
        const bf16x8 vb0 = *(const bf16x8*)&sVT[lq][ks * 16 + hi * 8];
        const bf16x8 vb1 = *(const bf16x8*)&sVT[32 + lq][ks * 16 + hi * 8];
        O0 = __builtin_amdgcn_mfma_f32_32x32x16_bf16(pa[ks], vb0, O0, 0, 0, 0);
        O1 = __builtin_amdgcn_mfma_f32_32x32x16_bf16(pa[ks], vb1, O1, 0, 0, 0);
    }
    __builtin_amdgcn_s_setprio(0);
}

__global__ __launch_bounds__(256, 3) void attn_kernel(
    const __bf16* __restrict__ qw, const __bf16* __restrict__ kw,
    const __bf16* __restrict__ vw, __bf16* __restrict__ ow)
{
    __shared__ __bf16 sK0[64][72], sVT0[64][72];
    __shared__ __bf16 sK1[64][72], sVT1[64][72];

    const int t    = threadIdx.x;
    const int lane = t & 63;
    const int w    = t >> 6;
    const int lq   = lane & 31;
    const int hi   = lane >> 5;

    const int bh  = blockIdx.y;
    const int b   = bh >> 5;
    const int h   = bh & 31;
    const int kvh = h >> 2;
    const int q0  = blockIdx.x * 128 + w * 32;

    bf16x8 bQ[4];
    {
        const __bf16* qrow = qw + (((size_t)b * S_ + q0 + lq) * H_ + h) * D_;
#pragma unroll
        for (int ks = 0; ks < 4; ++ks)
            bQ[ks] = *(const bf16x8*)(qrow + ks * 16 + hi * 8);
    }

    f32x16 O0, O1;
#pragma unroll
    for (int i = 0; i < 16; ++i) { O0[i] = 0.f; O1[i] = 0.f; }
    float lsum = 0.f;

    const __bf16* kbase = kw + ((size_t)b * S_ * HKV_ + kvh) * D_;
    const __bf16* vbase = vw + ((size_t)b * S_ * HKV_ + kvh) * D_;
    const int kkey = t >> 2,        kd  = (t & 3) * 16;
    const int vkp  = (t & 31) * 2,  vdg = (t >> 5) * 4;

    StageRegs sr;
    stage_load(sr, kbase, vbase, 0, kkey, kd, vkp, vdg);
    stage_write(sr, sK0, sVT0, kkey, kd, vkp, vdg);
    __syncthreads();

#pragma unroll 1
    for (int j0 = 0; j0 < S_; j0 += 128) {
        StageRegs nx;
        stage_load(nx, kbase, vbase, j0 + 64, kkey, kd, vkp, vdg);
        attn_tile(sK0, sVT0, bQ, lq, hi, O0, O1, lsum);
        stage_write(nx, sK1, sVT1, kkey, kd, vkp, vdg);
        __syncthreads();
        if (j0 + 128 < S_)
            stage_load(nx, kbase, vbase, j0 + 128, kkey, kd, vkp, vdg);
        attn_tile(sK1, sVT1, bQ, lq, hi, O0, O1, lsum);
        if (j0 + 128 < S_)
            stage_write(nx, sK0, sVT0, kkey, kd, vkp, vdg);
        __syncthreads();
    }

    lsum += __shfl_xor(lsum, 32);
    const float inv = 1.0f / lsum;

#pragma unroll
    for (int r = 0; r < 16; ++r) {
        const int   qr = (r & 3) + 8 * (r >> 2) + 4 * hi;
        const float li = __shfl(inv, qr);
        __bf16* orow = ow + (((size_t)b * S_ + q0 + qr) * H_ + h) * D_;
        orow[lq]      = (__bf16)(O0[r] * li);
        orow[32 + lq] = (__bf16)(O1[r] * li);
    }
}

// ---------------------------------------------------------------------------
extern "C" void kernel_launch(void* const* d_in, const int* in_sizes, int n_in,
                              void* d_out, int out_size, void* d_ws, size_t ws_size,
                              hipStream_t stream)
{
    const float* x  = (const float*)d_in[0];
    const float* fc = (const float*)d_in[2];
    const float* fs = (const float*)d_in[3];
    const float* wq = (const float*)d_in[4];
    const float* wk = (const float*)d_in[5];
    const float* wv = (const float*)d_in[6];
    const float* wo = (const float*)d_in[7];
    const float* obias = (const float*)d_in[8];
    float* out = (float*)d_out;

    __bf16* ws  = (__bf16*)d_ws;
    __bf16* xb  = ws;                                    // 4096*2048
    __bf16* wT  = xb  + (size_t)4096 * 2048;             // 3072*2048 [wq^T|wk^T|wv^T]
    __bf16* woT = wT  + (size_t)3072 * 2048;             // 2048*2048
    __bf16* qb  = woT + (size_t)2048 * 2048;             // B,S,H,D
    __bf16* kb  = qb  + (size_t)B_ * S_ * H_ * D_;       // B,S,HKV,D
    __bf16* vb  = kb  + (size_t)B_ * S_ * HKV_ * D_;
    __bf16* obf = vb  + (size_t)B_ * S_ * HKV_ * D_;     // B,S,H,D

    convert_kernel<<<4096, 256, 0, stream>>>(x, xb, 4096 * 2048 / 8);
    transpose_convert_all_kernel<<<dim3(160, 64), 256, 0, stream>>>(
        wq, wk, wv, wo, wT, woT);

    gemm_qkv_kernel<<<192, 512, 0, stream>>>(xb, wT, fc, fs, qb, kb, vb);

    attn_kernel<<<dim3(S_ / 128, B_ * H_), 256, 0, stream>>>(qb, kb, vb, obf);

    gemm_out_kernel<<<256, 512, 0, stream>>>(obf, woT, obias, out);
}

// Round 6
// 353.388 us; speedup vs baseline: 1.4002x; 1.0166x over previous
//
#include <hip/hip_runtime.h>
#include <math.h>

#define B_    2
#define S_    2048
#define E_    2048
#define H_    32
#define HKV_  8
#define D_    64

typedef __bf16 bf16x8 __attribute__((ext_vector_type(8)));
typedef float  f32x4  __attribute__((ext_vector_type(4)));
typedef float  f32x16 __attribute__((ext_vector_type(16)));
typedef unsigned int u32x2 __attribute__((ext_vector_type(2)));
typedef unsigned int u32x4 __attribute__((ext_vector_type(4)));

#define GPTR(x) ((const __attribute__((address_space(1))) void*)(x))
#define LPTR(x) ((__attribute__((address_space(3))) void*)(x))

// 0.125 * log2(e): folded into Q so attention softmax is exp2-direct.
#define QK_SCALE_LOG2E 0.18033688011112042f

// ---------------------------------------------------------------------------
// fp32 -> bf16 flat convert (x)
// ---------------------------------------------------------------------------
__global__ __launch_bounds__(256) void convert_kernel(
    const float* __restrict__ in, __bf16* __restrict__ out, int n8)
{
    const int i = blockIdx.x * 256 + threadIdx.x;
    if (i >= n8) return;
    const float4 a = ((const float4*)in)[i * 2];
    const float4 b = ((const float4*)in)[i * 2 + 1];
    bf16x8 o;
    o[0] = (__bf16)a.x; o[1] = (__bf16)a.y; o[2] = (__bf16)a.z; o[3] = (__bf16)a.w;
    o[4] = (__bf16)b.x; o[5] = (__bf16)b.y; o[6] = (__bf16)b.z; o[7] = (__bf16)b.w;
    ((bf16x8*)out)[i] = o;
}

// ---------------------------------------------------------------------------
// All 4 weight transposes (fp32 (K,N) -> bf16 (N,K)) in ONE dispatch.
// ---------------------------------------------------------------------------
__global__ __launch_bounds__(256) void transpose_convert_all_kernel(
    const float* __restrict__ wq, const float* __restrict__ wk,
    const float* __restrict__ wv, const float* __restrict__ wo,
    __bf16* __restrict__ wT, __bf16* __restrict__ woT)
{
    const float* in; __bf16* out; int N, xb;
    const int x = blockIdx.x;
    if (x < 64)      { in = wq; out = wT;                        N = 2048; xb = x; }
    else if (x < 80) { in = wk; out = wT + (size_t)2048 * 2048;  N = 512;  xb = x - 64; }
    else if (x < 96) { in = wv; out = wT + (size_t)2560 * 2048;  N = 512;  xb = x - 80; }
    else             { in = wo; out = woT;                       N = 2048; xb = x - 96; }
    const int K = 2048;

    __shared__ float tile[32][33];
    const int k0 = blockIdx.y * 32, n0 = xb * 32;
    const int r  = threadIdx.x >> 3;
    const int c4 = (threadIdx.x & 7) * 4;
    const float4 v = *(const float4*)&in[(size_t)(k0 + r) * N + n0 + c4];
    tile[r][c4 + 0] = v.x; tile[r][c4 + 1] = v.y;
    tile[r][c4 + 2] = v.z; tile[r][c4 + 3] = v.w;
    __syncthreads();
    ushort4 o;
    __bf16 h0 = (__bf16)tile[c4 + 0][r]; o.x = __builtin_bit_cast(unsigned short, h0);
    __bf16 h1 = (__bf16)tile[c4 + 1][r]; o.y = __builtin_bit_cast(unsigned short, h1);
    __bf16 h2 = (__bf16)tile[c4 + 2][r]; o.z = __builtin_bit_cast(unsigned short, h2);
    __bf16 h3 = (__bf16)tile[c4 + 3][r]; o.w = __builtin_bit_cast(unsigned short, h3);
    *(ushort4*)&out[(size_t)(n0 + r) * K + k0 + c4] = o;
}

// ---------------------------------------------------------------------------
// Pipelined GEMM (unchanged from R5: 4-slot ring, counted vmcnt, ~650 TF).
// ---------------------------------------------------------------------------
template<int BN> struct PG {
    static constexpr int BM     = 256;
    static constexpr int BK     = 32;
    static constexpr int ASLOT  = BM * BK;
    static constexpr int BSLOT  = BN * BK;
    static constexpr int SLOT   = ASLOT + BSLOT;
    static constexpr int BINSTR = BN / 128;
    static constexpr int L      = 2 + BINSTR;
    static constexpr int NJ     = BN / 64;
};

template<int BN>
__device__ __forceinline__ void stage_tile(
    const __bf16* __restrict__ A, const __bf16* __restrict__ Bt,
    int m0, int n0, int K, int T, __bf16* sl, int t, int wbase)
{
    using G = PG<BN>;
    const int k0   = T * G::BK;
    const int rsub = t >> 2;
    const int cp   = t & 3;
#pragma unroll
    for (int g = 0; g < 2; ++g) {
        const int row = g * 128 + rsub;
        const int cl  = cp ^ ((row >> 1) & 3);
        __builtin_amdgcn_global_load_lds(
            GPTR(A + (size_t)(m0 + row) * K + k0 + cl * 8),
            LPTR(sl + (g * 512 + wbase) * 8), 16, 0, 0);
    }
#pragma unroll
    for (int g = 0; g < G::BINSTR; ++g) {
        const int row = g * 128 + rsub;
        const int cl  = cp ^ ((row >> 1) & 3);
        __builtin_amdgcn_global_load_lds(
            GPTR(Bt + (size_t)(n0 + row) * K + k0 + cl * 8),
            LPTR(sl + G::ASLOT + (g * 512 + wbase) * 8), 16, 0, 0);
    }
}

template<int BN>
__device__ __forceinline__ void compute_tile(
    const __bf16* sl, int wrow, int wcol, int col, int quad,
    f32x4 acc[8][PG<BN>::NJ])
{
    using G = PG<BN>;
    bf16x8 af[8], bfr[G::NJ];
#pragma unroll
    for (int i = 0; i < 8; ++i) {
        const int m = wrow + i * 16 + col;
        af[i] = *(const bf16x8*)&sl[m * 32 + ((quad ^ ((m >> 1) & 3)) * 8)];
    }
#pragma unroll
    for (int j = 0; j < G::NJ; ++j) {
        const int n = wcol + j * 16 + col;
        bfr[j] = *(const bf16x8*)&sl[G::ASLOT + n * 32 + ((quad ^ ((n >> 1) & 3)) * 8)];
    }
    __builtin_amdgcn_s_setprio(1);
#pragma unroll
    for (int i = 0; i < 8; ++i)
#pragma unroll
        for (int j = 0; j < G::NJ; ++j)
            acc[i][j] = __builtin_amdgcn_mfma_f32_16x16x32_bf16(
                af[i], bfr[j], acc[i][j], 0, 0, 0);
    __builtin_amdgcn_s_setprio(0);
}

template<int BN>
__device__ __forceinline__ void gemm_pipe_body(
    const __bf16* __restrict__ A, const __bf16* __restrict__ Bt,
    int m0, int n0, int K, __bf16* sL, f32x4 acc[8][PG<BN>::NJ])
{
    using G = PG<BN>;
    const int t     = threadIdx.x;
    const int wbase = t & ~63;
    const int lane  = t & 63;
    const int col   = lane & 15;
    const int quad  = lane >> 4;
    const int w     = t >> 6;
    const int wrow  = (w >> 2) * 128;
    const int wcol  = (w & 3) * (BN / 4);
    const int NT    = K / G::BK;

    stage_tile<BN>(A, Bt, m0, n0, K, 0, sL + 0 * G::SLOT, t, wbase);
    stage_tile<BN>(A, Bt, m0, n0, K, 1, sL + 1 * G::SLOT, t, wbase);
    stage_tile<BN>(A, Bt, m0, n0, K, 2, sL + 2 * G::SLOT, t, wbase);

    int T = 0;
#pragma unroll 1
    for (; T < NT - 3; ++T) {
        asm volatile("s_waitcnt vmcnt(%0)" :: "n"(2 * G::L) : "memory");
        __builtin_amdgcn_s_barrier();
        stage_tile<BN>(A, Bt, m0, n0, K, T + 3, sL + ((T + 3) & 3) * G::SLOT, t, wbase);
        compute_tile<BN>(sL + (T & 3) * G::SLOT, wrow, wcol, col, quad, acc);
    }
    asm volatile("s_waitcnt vmcnt(%0)" :: "n"(2 * G::L) : "memory");
    __builtin_amdgcn_s_barrier();
    compute_tile<BN>(sL + (T & 3) * G::SLOT, wrow, wcol, col, quad, acc); ++T;
    asm volatile("s_waitcnt vmcnt(%0)" :: "n"(G::L) : "memory");
    __builtin_amdgcn_s_barrier();
    compute_tile<BN>(sL + (T & 3) * G::SLOT, wrow, wcol, col, quad, acc); ++T;
    asm volatile("s_waitcnt vmcnt(0)" ::: "memory");
    __builtin_amdgcn_s_barrier();
    compute_tile<BN>(sL + (T & 3) * G::SLOT, wrow, wcol, col, quad, acc);
}

// ---------------------------------------------------------------------------
// QKV GEMM (BM=256, BN=256): 192 blocks, fused RoPE/scale epilogue.
// ---------------------------------------------------------------------------
__global__ __launch_bounds__(512, 2) void gemm_qkv_kernel(
    const __bf16* __restrict__ xb, const __bf16* __restrict__ wT,
    const float* __restrict__ fc, const float* __restrict__ fs,
    __bf16* __restrict__ qb, __bf16* __restrict__ kb, __bf16* __restrict__ vb)
{
    __shared__ __bf16 sL[4 * PG<256>::SLOT];   // 128 KiB
    f32x4 acc[8][4];
#pragma unroll
    for (int i = 0; i < 8; ++i)
#pragma unroll
        for (int j = 0; j < 4; ++j) acc[i][j] = (f32x4){0.f, 0.f, 0.f, 0.f};

    const int lin     = blockIdx.x;
    const int logical = (lin & 7) * 24 + (lin >> 3);
    const int bx      = logical % 12;
    const int m0      = (logical / 12) * 256;
    const int n0      = bx * 256;

    gemm_pipe_body<256>(xb, wT, m0, n0, E_, sL, acc);

    __bf16* Cp; int ldc, base;
    if (bx < 8)       { Cp = qb; ldc = H_ * D_;   base = 0;    }
    else if (bx < 10) { Cp = kb; ldc = HKV_ * D_; base = 2048; }
    else              { Cp = vb; ldc = HKV_ * D_; base = 2560; }
    const bool  doRope = (bx < 10);
    const float qsc    = (bx < 8) ? QK_SCALE_LOG2E : 1.0f;

    const int t    = threadIdx.x;
    const int lane = t & 63;
    const int col  = lane & 15;
    const int quad = lane >> 4;
    const int w    = t >> 6;
    const int wrow = (w >> 2) * 128;
    const int wcol = (w & 3) * 64;
#pragma unroll
    for (int i = 0; i < 8; ++i)
#pragma unroll
        for (int j = 0; j < 4; ++j)
#pragma unroll
            for (int r = 0; r < 4; ++r) {
                const int m  = m0 + wrow + i * 16 + quad * 4 + r;
                const int ng = n0 + wcol + j * 16 + col;
                float val = acc[i][j][r] * qsc;
                if (doRope) {
                    const int   s    = m & (S_ - 1);
                    const int   pair = (ng & 63) >> 1;
                    const float c    = fc[s * 32 + pair];
                    const float sn   = fs[s * 32 + pair];
                    const float oth  = __shfl_xor(val, 1);
                    val = (lane & 1) ? (oth * sn + val * c)
                                     : (val * c - oth * sn);
                }
                Cp[(size_t)m * ldc + (ng - base)] = (__bf16)val;
            }
}

// ---------------------------------------------------------------------------
// Output GEMM (BM=256, BN=128): 256 blocks, bias epilogue.
// ---------------------------------------------------------------------------
__global__ __launch_bounds__(512, 2) void gemm_out_kernel(
    const __bf16* __restrict__ ob, const __bf16* __restrict__ woT,
    const float* __restrict__ bias, float* __restrict__ out)
{
    __shared__ __bf16 sL[4 * PG<128>::SLOT];   // 96 KiB
    f32x4 acc[8][2];
#pragma unroll
    for (int i = 0; i < 8; ++i)
#pragma unroll
        for (int j = 0; j < 2; ++j) acc[i][j] = (f32x4){0.f, 0.f, 0.f, 0.f};

    const int lin     = blockIdx.x;
    const int logical = (lin & 7) * 32 + (lin >> 3);
    const int n0      = (logical % 16) * 128;
    const int m0      = (logical / 16) * 256;

    gemm_pipe_body<128>(ob, woT, m0, n0, H_ * D_, sL, acc);

    const int t    = threadIdx.x;
    const int lane = t & 63;
    const int col  = lane & 15;
    const int quad = lane >> 4;
    const int w    = t >> 6;
    const int wrow = (w >> 2) * 128;
    const int wcol = (w & 3) * 32;
#pragma unroll
    for (int i = 0; i < 8; ++i)
#pragma unroll
        for (int j = 0; j < 2; ++j)
#pragma unroll
            for (int r = 0; r < 4; ++r) {
                const int m = m0 + wrow + i * 16 + quad * 4 + r;
                const int n = n0 + wcol + j * 16 + col;
                out[(size_t)m * E_ + n] = acc[i][j][r] + bias[n];
            }
}

// ---------------------------------------------------------------------------
// MFMA flash attention v4: dual-chain QK^T for ILP.
// Change vs R5 (113 µs, MfmaUtil 26%): the two key-halves (kb=0: keys 0-31,
// kb=1: keys 32-63) were serialized -- each a 4-deep dependent MFMA chain,
// then exp2, then pack, then PV; setprio brackets blocked cross-kb
// interleave. Now p0/p1 accumulate as two INDEPENDENT chains inside one
// setprio region (2x MFMA ILP), all 32 exp2 form one block, and the 8 V
// ds_reads issue right after QK so their latency hides under softmax VALU.
// __launch_bounds__(256) (no min-wave arg): allocator freedom for the extra
// ~16 live VGPRs; (256,4) spilled 287 MB (R3), (256,3) capped at 84 VGPR.
// Spill tripwire: WRITE_SIZE must stay 16 MB.
// ---------------------------------------------------------------------------
struct StageRegs {
    bf16x8  k0, k1;
    ushort4 va0, vc0, va1, vc1;
};

__device__ __forceinline__ void stage_load(
    StageRegs& r, const __bf16* kbase, const __bf16* vbase, int j0,
    int kkey, int kd, int vkp, int vdg)
{
    const int KSTR = HKV_ * D_;   // 512
    const __bf16* kr = kbase + (size_t)(j0 + kkey) * KSTR + kd;
    r.k0 = ((const bf16x8*)kr)[0];
    r.k1 = ((const bf16x8*)kr)[1];
    const __bf16* v0 = vbase + (size_t)(j0 + vkp) * KSTR + vdg;
    r.va0 = *(const ushort4*)(v0);
    r.vc0 = *(const ushort4*)(v0 + KSTR);
    r.va1 = *(const ushort4*)(v0 + 32);
    r.vc1 = *(const ushort4*)(v0 + KSTR + 32);
}

__device__ __forceinline__ void stage_write(
    const StageRegs& r, __bf16 (*sK)[72], __bf16 (*sVT)[72],
    int kkey, int kd, int vkp, int vdg)
{
    *(bf16x8*)&sK[kkey][kd]     = r.k0;
    *(bf16x8*)&sK[kkey][kd + 8] = r.k1;
    *(unsigned int*)&sVT[vdg + 0][vkp]      = ((unsigned)r.vc0.x << 16) | r.va0.x;
    *(unsigned int*)&sVT[vdg + 1][vkp]      = ((unsigned)r.vc0.y << 16) | r.va0.y;
    *(unsigned int*)&sVT[vdg + 2][vkp]      = ((unsigned)r.vc0.z << 16) | r.va0.z;
    *(unsigned int*)&sVT[vdg + 3][vkp]      = ((unsigned)r.vc0.w << 16) | r.va0.w;
    *(unsigned int*)&sVT[vdg + 32 + 0][vkp] = ((unsigned)r.vc1.x << 16) | r.va1.x;
    *(unsigned int*)&sVT[vdg + 32 + 1][vkp] = ((unsigned)r.vc1.y << 16) | r.va1.y;
    *(unsigned int*)&sVT[vdg + 32 + 2][vkp] = ((unsigned)r.vc1.z << 16) | r.va1.z;
    *(unsigned int*)&sVT[vdg + 32 + 3][vkp] = ((unsigned)r.vc1.w << 16) | r.va1.w;
}

__device__ __forceinline__ bf16x8 pack_pa(const f32x16& p, int i0)
{
    unsigned a0, a1, a2, a3;
    asm("v_cvt_pk_bf16_f32 %0, %1, %2" : "=v"(a0) : "v"(p[i0 + 0]), "v"(p[i0 + 1]));
    asm("v_cvt_pk_bf16_f32 %0, %1, %2" : "=v"(a1) : "v"(p[i0 + 2]), "v"(p[i0 + 3]));
    asm("v_cvt_pk_bf16_f32 %0, %1, %2" : "=v"(a2) : "v"(p[i0 + 4]), "v"(p[i0 + 5]));
    asm("v_cvt_pk_bf16_f32 %0, %1, %2" : "=v"(a3) : "v"(p[i0 + 6]), "v"(p[i0 + 7]));
    const u32x2 s02 = __builtin_amdgcn_permlane32_swap(a0, a2, false, false);
    const u32x2 s13 = __builtin_amdgcn_permlane32_swap(a1, a3, false, false);
    return __builtin_bit_cast(bf16x8, (u32x4){s02[0], s13[0], s02[1], s13[1]});
}

__device__ __forceinline__ void attn_tile(
    const __bf16 (*sK)[72], const __bf16 (*sVT)[72],
    const bf16x8* bQ, int lq, int hi,
    f32x16& O0, f32x16& O1, float& lsum)
{
    // --- QK^T: two independent accumulation chains (keys 0-31 / 32-63)
    f32x16 p0, p1;
#pragma unroll
    for (int i = 0; i < 16; ++i) { p0[i] = 0.f; p1[i] = 0.f; }
    __builtin_amdgcn_s_setprio(1);
#pragma unroll
    for (int ks = 0; ks < 4; ++ks) {
        const bf16x8 aK0 = *(const bf16x8*)&sK[lq][ks * 16 + hi * 8];
        const bf16x8 aK1 = *(const bf16x8*)&sK[32 + lq][ks * 16 + hi * 8];
        p0 = __builtin_amdgcn_mfma_f32_32x32x16_bf16(aK0, bQ[ks], p0, 0, 0, 0);
        p1 = __builtin_amdgcn_mfma_f32_32x32x16_bf16(aK1, bQ[ks], p1, 0, 0, 0);
    }
    __builtin_amdgcn_s_setprio(0);

    // --- issue V fragment reads early: latency hides under softmax VALU
    bf16x8 vbf[8];
#pragma unroll
    for (int ks = 0; ks < 4; ++ks) {
        vbf[ks * 2]     = *(const bf16x8*)&sVT[lq][ks * 16 + hi * 8];
        vbf[ks * 2 + 1] = *(const bf16x8*)&sVT[32 + lq][ks * 16 + hi * 8];
    }

    // --- softmax: 32 independent exp2, running denominator
    float ps = 0.f;
#pragma unroll
    for (int i = 0; i < 16; ++i) {
        p0[i] = __builtin_amdgcn_exp2f(p0[i]);
        p1[i] = __builtin_amdgcn_exp2f(p1[i]);
        ps += p0[i] + p1[i];
    }
    lsum += ps;

    bf16x8 pa[4];
    pa[0] = pack_pa(p0, 0);
    pa[1] = pack_pa(p0, 8);
    pa[2] = pack_pa(p1, 0);
    pa[3] = pack_pa(p1, 8);

    // --- PV: A = PA (regs), B = V^T (regs, preloaded)
    __builtin_amdgcn_s_setprio(1);
#pragma unroll
    for (int ks = 0; ks < 4; ++ks) {
        O0 = __builtin_amdgcn_mfma_f32_32x32x16_bf16(pa[ks], vbf[ks * 2],     O0, 0, 0, 0);
        O1 = __builtin_amdgcn_mfma_f32_32x32x16_bf16(pa[ks], vbf[ks * 2 + 1], O1, 0, 0, 0);
    }
    __builtin_amdgcn_s_setprio(0);
}

__global__ __launch_bounds__(256) void attn_kernel(
    const __bf16* __restrict__ qw, const __bf16* __restrict__ kw,
    const __bf16* __restrict__ vw, __bf16* __restrict__ ow)
{
    __shared__ __bf16 sK0[64][72], sVT0[64][72];
    __shared__ __bf16 sK1[64][72], sVT1[64][72];

    const int t    = threadIdx.x;
    const int lane = t & 63;
    const int w    = t >> 6;
    const int lq   = lane & 31;
    const int hi   = lane >> 5;

    const int bh  = blockIdx.y;
    const int b   = bh >> 5;
    const int h   = bh & 31;
    const int kvh = h >> 2;
    const int q0  = blockIdx.x * 128 + w * 32;

    bf16x8 bQ[4];
    {
        const __bf16* qrow = qw + (((size_t)b * S_ + q0 + lq) * H_ + h) * D_;
#pragma unroll
        for (int ks = 0; ks < 4; ++ks)
            bQ[ks] = *(const bf16x8*)(qrow + ks * 16 + hi * 8);
    }

    f32x16 O0, O1;
#pragma unroll
    for (int i = 0; i < 16; ++i) { O0[i] = 0.f; O1[i] = 0.f; }
    float lsum = 0.f;

    const __bf16* kbase = kw + ((size_t)b * S_ * HKV_ + kvh) * D_;
    const __bf16* vbase = vw + ((size_t)b * S_ * HKV_ + kvh) * D_;
    const int kkey = t >> 2,        kd  = (t & 3) * 16;
    const int vkp  = (t & 31) * 2,  vdg = (t >> 5) * 4;

    StageRegs sr;
    stage_load(sr, kbase, vbase, 0, kkey, kd, vkp, vdg);
    stage_write(sr, sK0, sVT0, kkey, kd, vkp, vdg);
    __syncthreads();

#pragma unroll 1
    for (int j0 = 0; j0 < S_; j0 += 128) {
        StageRegs nx;
        stage_load(nx, kbase, vbase, j0 + 64, kkey, kd, vkp, vdg);
        attn_tile(sK0, sVT0, bQ, lq, hi, O0, O1, lsum);
        stage_write(nx, sK1, sVT1, kkey, kd, vkp, vdg);
        __syncthreads();
        if (j0 + 128 < S_)
            stage_load(nx, kbase, vbase, j0 + 128, kkey, kd, vkp, vdg);
        attn_tile(sK1, sVT1, bQ, lq, hi, O0, O1, lsum);
        if (j0 + 128 < S_)
            stage_write(nx, sK0, sVT0, kkey, kd, vkp, vdg);
        __syncthreads();
    }

    lsum += __shfl_xor(lsum, 32);
    const float inv = 1.0f / lsum;

#pragma unroll
    for (int r = 0; r < 16; ++r) {
        const int   qr = (r & 3) + 8 * (r >> 2) + 4 * hi;
        const float li = __shfl(inv, qr);
        __bf16* orow = ow + (((size_t)b * S_ + q0 + qr) * H_ + h) * D_;
        orow[lq]      = (__bf16)(O0[r] * li);
        orow[32 + lq] = (__bf16)(O1[r] * li);
    }
}

// ---------------------------------------------------------------------------
extern "C" void kernel_launch(void* const* d_in, const int* in_sizes, int n_in,
                              void* d_out, int out_size, void* d_ws, size_t ws_size,
                              hipStream_t stream)
{
    const float* x  = (const float*)d_in[0];
    const float* fc = (const float*)d_in[2];
    const float* fs = (const float*)d_in[3];
    const float* wq = (const float*)d_in[4];
    const float* wk = (const float*)d_in[5];
    const float* wv = (const float*)d_in[6];
    const float* wo = (const float*)d_in[7];
    const float* obias = (const float*)d_in[8];
    float* out = (float*)d_out;

    __bf16* ws  = (__bf16*)d_ws;
    __bf16* xb  = ws;                                    // 4096*2048
    __bf16* wT  = xb  + (size_t)4096 * 2048;             // 3072*2048 [wq^T|wk^T|wv^T]
    __bf16* woT = wT  + (size_t)3072 * 2048;             // 2048*2048
    __bf16* qb  = woT + (size_t)2048 * 2048;             // B,S,H,D
    __bf16* kb  = qb  + (size_t)B_ * S_ * H_ * D_;       // B,S,HKV,D
    __bf16* vb  = kb  + (size_t)B_ * S_ * HKV_ * D_;
    __bf16* obf = vb  + (size_t)B_ * S_ * HKV_ * D_;     // B,S,H,D

    convert_kernel<<<4096, 256, 0, stream>>>(x, xb, 4096 * 2048 / 8);
    transpose_convert_all_kernel<<<dim3(160, 64), 256, 0, stream>>>(
        wq, wk, wv, wo, wT, woT);

    gemm_qkv_kernel<<<192, 512, 0, stream>>>(xb, wT, fc, fs, qb, kb, vb);

    attn_kernel<<<dim3(S_ / 128, B_ * H_), 256, 0, stream>>>(qb, kb, vb, obf);

    gemm_out_kernel<<<256, 512, 0, stream>>>(obf, woT, obias, out);
}